// Round 8
// baseline (132.713 us; speedup 1.0000x reference)
//
#include <hip/hip_runtime.h>
#include <math.h>

// TOF PET forward projection.
// History: R3 97us proj (L2 thrash) -> R4 Morton sort FETCH 215->26MB ->
// R6 4 lanes/LOR: proj 67 -> R7 sorted records + 8 lanes: proj 50 -> R8
// exact-fast-path voxel divide: 44.5 -> R9 unroll: NEUTRAL -> R10 affine
// index: NEUTRAL -> R11 2x2x4 brick gather: proj ~42-44 -> R12 coop fused
// setup: FAILED (grid.sync = 325us; NEVER grid.sync-fuse here) -> R13
// scan+brickify one dispatch: 133.9 WIN -> R14 guard 1e-3->3e-4 (wave-level
// fallback 32%->11%): 132.2. proj now ~41us = gather-latency floor; VALU
// attacks exhausted (R8/R9/R10/R14 all small/neutral past 44).
// R15: setup attack. scatter was scattered-WRITE-bound (48B/LOR random,
// 9.6MB + duplicate slab_clip). Split what/where: (a) bucketrec fuses
// record-build into bucket, records written in INPUT order (coalesced);
// (b) perm kernel: slot=atomicAdd(offsets[key]); perm[slot]=i (4B random,
// 0.8MB); (c) proj reads lor=perm[gid] (coalesced) then rec at random slot
// (L2-resident, once per LOR, latency-hidden). Per-LOR values bit-identical
// (only within-bucket rank order changes; never affected values).
// Budget @132.2: fill ~45 (harness, fixed) | proj ~41 | setup+gaps ~46.
// Index-path math STRICTLY UNFUSED exact-rn f32 — DO NOT approximate or
// contract (R0-R2: voxel flips => absmax 0.14 > 0.071 threshold). Affine
// guard 3e-4 with exact-chain fallback (R14, bound 1.16e-4, 2.6x margin).
// Summation order free (validated R4/R5/R6).

#define NB_POS 4096          // 16^3 Morton cells, 25 mm
#define NCLS   8             // window-length classes (16-sample bins)
#define NBUCK  (NB_POS * NCLS)
#define SPL    8             // lanes per LOR

__device__ __forceinline__ int morton4(int x, int y, int z) {
    int m = 0;
#pragma unroll
    for (int b = 0; b < 4; ++b) {
        m |= ((x >> b) & 1) << (3 * b + 0);
        m |= ((y >> b) & 1) << (3 * b + 1);
        m |= ((z >> b) & 1) << (3 * b + 2);
    }
    return m;
}

// floor(rn(xs/3.125)) bit-identically, cheaply (R8-validated):
// q=xs*0.32f agrees with rn(xs/3.125) to <2.3e-5 abs; floor can only differ
// within 1e-4 of an integer boundary -> exact IEEE '/' there (~2e-4/coord).
__device__ __forceinline__ float floor_div3125(float xs) {
#pragma clang fp contract(off)
    float q  = xs * 0.32f;
    float fq = floorf(q);
    float f  = q - fq;                      // exact (Sterbenz-range)
    if (__builtin_expect(f < 1e-4f || f > 0.9999f, 0)) {
        fq = floorf(xs / 3.125f);           // exact rn div — rare path
    }
    return fq;
}

__device__ __forceinline__ int vox_of(float xs) {
    const float fq = floor_div3125(xs);
    return min(max((int)fq, 0), 127);
}

// Slab clip (strictly unfused, exact rn divs — reference-visible tmin/span).
__device__ __forceinline__ void slab_clip(
    float p1x, float p1y, float p1z, float dx, float dy, float dz,
    float& tmin, float& tmax)
{
    const float eps = 1e-8f;
    float sdx = (fabsf(dx) < eps) ? eps : dx;
    float sdy = (fabsf(dy) < eps) ? eps : dy;
    float sdz = (fabsf(dz) < eps) ? eps : dz;
    float tax = (-200.f - p1x) / sdx, tbx = (200.f - p1x) / sdx;
    float tay = (-200.f - p1y) / sdy, tby = (200.f - p1y) / sdy;
    float taz = (-200.f - p1z) / sdz, tbz = (200.f - p1z) / sdz;
    tmin = fmaxf(fmaxf(fmaxf(fminf(tax, tbx), fminf(tay, tby)),
                       fminf(taz, tbz)), 0.f);
    tmax = fminf(fminf(fminf(fmaxf(tax, tbx), fmaxf(tay, tby)),
                       fmaxf(taz, tbz)), 1.f);
}

// Fused bucket + record build. Records written in INPUT order (coalesced);
// key -> tmp + counts. Record math verbatim from the validated scatter.
__global__ void bucketrec_kernel(const float* __restrict__ lors,
                                 int* __restrict__ counts,
                                 int* __restrict__ tmp,
                                 float4* __restrict__ recS,  // {tmin,span,L,pk}
                                 float4* __restrict__ ls8,   // 2 per LOR
                                 int n) {
#pragma clang fp contract(off)
    int i = blockIdx.x * 256 + threadIdx.x;
    if (i >= n) return;
    const float* lp = lors + (size_t)i * 7;
    float p1x = lp[0], p1y = lp[1], p1z = lp[2];
    float p2x = lp[3], p2y = lp[4], p2z = lp[5];
    float tt = lp[6];
    float dx = p2x - p1x, dy = p2y - p1y, dz = p2z - p1z;
    float L = sqrtf(((dx * dx) + (dy * dy)) + (dz * dz));

    float tmin, tmax;
    slab_clip(p1x, p1y, p1z, dx, dy, dz, tmin, tmax);

    unsigned key;
    float span, recL;
    int jlo, jhi;
    if (!(tmax > tmin) || !(L > 0.f)) {
        // Invalids: spread uniformly (kills R5's one-bucket atomic storm).
        key = (unsigned)i & (NBUCK - 1);
        tmin = 0.f; span = 0.f; recL = 0.f; jlo = 0; jhi = -1;
    } else {
        span = tmax - tmin;
        recL = L;
        // sort key (approx math OK — key only)
        float tc = fminf(fmaxf(0.5f + tt / L, tmin), tmax);
        float px = p1x + tc * dx, py = p1y + tc * dy, pz = p1z + tc * dz;
        int cx = (int)fminf(fmaxf((px + 200.f) * 0.04f, 0.f), 15.f);
        int cy = (int)fminf(fmaxf((py + 200.f) * 0.04f, 0.f), 15.f);
        int cz = (int)fminf(fmaxf((pz + 200.f) * 0.04f, 0.f), 15.f);
        float jla = ((0.5f + (tt - 90.f) / L) - tmin) / span * 128.f;
        float jha = ((0.5f + (tt + 90.f) / L) - tmin) / span * 128.f;
        jla = fmaxf(jla, 0.f); jha = fminf(jha, 128.f);
        float wlen = fmaxf(jha - jla, 0.f);
        int cls = min(NCLS - 1, (int)(wlen * (1.f / 16.f)));
        key = ((unsigned)morton4(cx, cy, cz) << 3) | (unsigned)cls;
        // EXACT sample range (verbatim validated scatter math, unfused)
        const float tlo = 0.5f + (tt - 90.0f) / L;
        const float thi = 0.5f + (tt + 90.0f) / L;
        float jl = ((tlo - tmin) / span) * 128.0f - 0.5f;
        float jh = ((thi - tmin) / span) * 128.0f - 0.5f;
        jl = fminf(fmaxf(jl - 2.0f, 0.0f), 127.0f);
        jh = fminf(fmaxf(jh + 2.0f, -1.0f), 127.0f);
        jlo = (int)jl;
        jhi = (int)ceilf(jh);
        if (jhi > 127) jhi = 127;
    }
    atomicAdd(&counts[key], 1);
    tmp[i] = (int)key;
    const int pk = (jlo << 16) | (jhi & 0xFFFF);
    recS[i] = make_float4(tmin, span, recL, __int_as_float(pk));
    ls8[2 * i + 0] = make_float4(p1x, p1y, p1z, p2x);
    ls8[2 * i + 1] = make_float4(p2y, p2z, tt, __int_as_float(i));
}

// Fused: block 0 = 1024-thread scan of NBUCK counts -> exclusive offsets;
// blocks 1..2048 = brickify (2x2x4 bricks, one 64B line each). Independent
// work, no grid sync — consumers launch after completion.
__global__ __launch_bounds__(1024) void scan_brick_kernel(
    const int* __restrict__ counts, int* __restrict__ offsets,
    const float* __restrict__ image, float* __restrict__ bimg) {
    if (blockIdx.x == 0) {
        __shared__ int s[1024];
        int t = threadIdx.x;
        const int PER = NBUCK / 1024;
        int base = t * PER;
        int local[PER];
        int sum = 0;
#pragma unroll
        for (int i = 0; i < PER; ++i) {
            local[i] = counts[base + i]; sum += local[i];
        }
        s[t] = sum;
        __syncthreads();
        for (int off = 1; off < 1024; off <<= 1) {
            int v = (t >= off) ? s[t - off] : 0;
            __syncthreads();
            s[t] += v;
            __syncthreads();
        }
        int excl = (t == 0) ? 0 : s[t - 1];
#pragma unroll
        for (int i = 0; i < PER; ++i) {
            offsets[base + i] = excl; excl += local[i];
        }
    } else {
        // brickify: o = output (bricked) index, coalesced writes
        const int o = (int)(blockIdx.x - 1) * 1024 + (int)threadIdx.x;
        const int off = o & 15;
        const int brick = o >> 4;
        const int bz = brick & 31;
        const int t2 = brick >> 5;
        const int by = t2 & 63;
        const int bx = t2 >> 6;
        const int oz = off & 3, oy = (off >> 2) & 1, ox = off >> 3;
        const int vx = (bx << 1) | ox, vy = (by << 1) | oy,
                  vz = (bz << 2) | oz;
        bimg[o] = image[(((vx << 7) | vy) << 7) | vz];
    }
}

// Non-brick fallback scan (plain).
__global__ void scan_kernel(const int* __restrict__ counts,
                            int* __restrict__ offsets) {
    __shared__ int s[1024];
    int t = threadIdx.x;
    const int PER = NBUCK / 1024;
    int base = t * PER;
    int local[PER];
    int sum = 0;
#pragma unroll
    for (int i = 0; i < PER; ++i) { local[i] = counts[base + i]; sum += local[i]; }
    s[t] = sum;
    __syncthreads();
    for (int off = 1; off < 1024; off <<= 1) {
        int v = (t >= off) ? s[t - off] : 0;
        __syncthreads();
        s[t] += v;
        __syncthreads();
    }
    int excl = (t == 0) ? 0 : s[t - 1];
#pragma unroll
    for (int i = 0; i < PER; ++i) { offsets[base + i] = excl; excl += local[i]; }
}

// Permutation scatter: 4B random write per LOR (replaces 48B record scatter).
__global__ void perm_kernel(const int* __restrict__ tmp,
                            int* __restrict__ offsets,
                            int* __restrict__ perm, int n) {
    int i = blockIdx.x * 256 + threadIdx.x;
    if (i >= n) return;
    const int slot = atomicAdd(&offsets[tmp[i]], 1);
    perm[slot] = i;
}

// Standalone brickify (fallback path only).
__global__ __launch_bounds__(256) void brickify_kernel(
    const float* __restrict__ image, float* __restrict__ bimg) {
    const int o = blockIdx.x * 256 + threadIdx.x;
    const int off = o & 15;
    const int brick = o >> 4;
    const int bz = brick & 31;
    const int t  = brick >> 5;
    const int by = t & 63;
    const int bx = t >> 6;
    const int oz = off & 3, oy = (off >> 2) & 1, ox = off >> 3;
    const int vx = (bx << 1) | ox, vy = (by << 1) | oy, vz = (bz << 2) | oz;
    bimg[o] = image[(((vx << 7) | vy) << 7) | vz];
}

template <bool BRICK>
__global__ __launch_bounds__(256) void proj_kernel(
    const float* __restrict__ img,     // bricked if BRICK, else linear
    const float4* __restrict__ recS,   // input-order records
    const float4* __restrict__ ls8,
    const int* __restrict__ perm,      // sorted slot -> LOR id
    float* __restrict__ out,
    int n_lors, int chunks)
{
#pragma clang fp contract(off)
    const int b = blockIdx.x;
    const int sb = (b & 7) * chunks + (b >> 3);    // XCD swizzle
    const int idx = sb * 256 + (int)threadIdx.x;
    const int gid = idx >> 3;          // sorted LOR slot
    const int s   = idx & 7;           // sub-lane 0..7
    if (gid >= n_lors) return;

    const int lor = perm[gid];         // coalesced (consecutive gid)

    const float4 a  = ls8[2 * lor + 0];    // random slot, L2-resident
    const float4 c  = ls8[2 * lor + 1];
    const float4 r  = recS[lor];
    const float p1x = a.x, p1y = a.y, p1z = a.z;
    const float dx = a.w - p1x, dy = c.x - p1y, dz = c.y - p1z;
    const float ttof = c.z;
    const int   orig = __float_as_int(c.w);
    const float tmin = r.x, span = r.y, L = r.z;
    const int   pk   = __float_as_int(r.w);
    const int   jlo  = pk >> 16;
    const int   jhi  = (int)(short)(pk & 0xFFFF);

    // Affine constants: Q = C0 + al*C1 ~ ((p1 + t*d) + 200)*0.32 chain.
    // Rigorous worst-case |Q - ref_chain| <= 1.16e-4 voxel units (R14).
    const float sd  = span * 0.0078125f;            // span/128 (exact scale)
    const float C1x = (sd * dx) * 0.32f;
    const float C1y = (sd * dy) * 0.32f;
    const float C1z = (sd * dz) * 0.32f;
    const float C0x = ((p1x + (tmin * dx)) + 200.0f) * 0.32f;
    const float C0y = ((p1y + (tmin * dy)) + 200.0f) * 0.32f;
    const float C0z = ((p1z + (tmin * dz)) + 200.0f) * 0.32f;
    const float D1  = sd * L;
    const float D0  = ((tmin - 0.5f) * L) - ttof;

    float acc0 = 0.0f, acc1 = 0.0f;

    // Guard 3e-4 (2.6x margin on 1.16e-4 bound): wave-level fallback ~11%.
    auto sample = [&](float al, float& acc) {
        const float Qx = fmaf(al, C1x, C0x);
        const float Qy = fmaf(al, C1y, C0y);
        const float Qz = fmaf(al, C1z, C0z);
        float fx = floorf(Qx), fy = floorf(Qy), fz = floorf(Qz);
        const float rx = Qx - fx, ry = Qy - fy, rz = Qz - fz;
        const float rmn = fminf(fminf(rx, ry), rz);    // v_min3
        const float rmx = fmaxf(fmaxf(rx, ry), rz);    // v_max3
        if (__builtin_expect(rmn < 3e-4f || rmx > 0.9997f, 0)) {
            // EXACT reference chain (unfused, exact-rn):
            const float fr = al * 0.0078125f;          // ((float)j+0.5f)/128
            const float t  = tmin + (fr * span);
            const float ex = p1x + (t * dx);
            const float ey = p1y + (t * dy);
            const float ez = p1z + (t * dz);
            fx = floor_div3125(ex + 200.0f);           // == floorf(./3.125)
            fy = floor_div3125(ey + 200.0f);
            fz = floor_div3125(ez + 200.0f);
        }
        // clamp in float (v_med3), then convert
        const int vx = (int)fminf(fmaxf(fx, 0.0f), 127.0f);
        const int vy = (int)fminf(fmaxf(fy, 0.0f), 127.0f);
        const int vz = (int)fminf(fmaxf(fz, 0.0f), 127.0f);

        int vidx;
        if (BRICK) {
            vidx = ((((((vx >> 1) << 6) | (vy >> 1)) << 5) | (vz >> 2)) << 4)
                   | ((vx & 1) << 3) | ((vy & 1) << 2) | (vz & 3);
        } else {
            vidx = (((vx << 7) | vy) << 7) | vz;
        }
        const float val = img[vidx];

        const float dev = fmaf(al, D1, D0);            // weight path: approx OK
        const float w = (fabsf(dev) <= 90.0f)
            ? 0.06649038f * __expf((dev * dev) * (-5.5555556e-4f)) : 0.0f;
        acc = fmaf(val, w, acc);
    };

    float al = (float)(jlo + s) + 0.5f;                // exact
    int j = jlo + s;
    for (; j + SPL <= jhi; j += 2 * SPL) {
        sample(al, acc0);
        sample(al + 8.0f, acc1);                       // exact (int+0.5 range)
        al += 16.0f;
    }
    if (j <= jhi) sample(al, acc0);                    // <=1 remainder

    float acc = acc0 + acc1;   // summation order free (validated R4/R5/R6)

    // combine 8 sub-lanes
    acc += __shfl_xor(acc, 1, 64);
    acc += __shfl_xor(acc, 2, 64);
    acc += __shfl_xor(acc, 4, 64);

    if (s == 0) {
        // step = (span*L)/128: *0.0078125f bit-identical
        const float step = (span * L) * 0.0078125f;
        out[orig] = acc * step;
    }
}

// Fallback (ws too small): self-contained thread-per-LOR, unsorted.
__global__ __launch_bounds__(256) void proj_fallback(
    const float* __restrict__ image,
    const float* __restrict__ lors,
    float* __restrict__ out, int n_lors)
{
#pragma clang fp contract(off)
    const int lor = blockIdx.x * 256 + threadIdx.x;
    if (lor >= n_lors) return;
    const float* lp = lors + (size_t)lor * 7;
    const float p1x = lp[0], p1y = lp[1], p1z = lp[2];
    const float dx = lp[3] - p1x, dy = lp[4] - p1y, dz = lp[5] - p1z;
    const float ttof = lp[6];
    const float L = sqrtf(((dx * dx) + (dy * dy)) + (dz * dz));
    float tmin, tmax;
    slab_clip(p1x, p1y, p1z, dx, dy, dz, tmin, tmax);
    const float span = fmaxf(tmax - tmin, 0.0f);
    if (!(tmax > tmin)) { out[lor] = 0.0f; return; }
    float acc = 0.0f;
    for (int j = 0; j < 128; ++j) {
        const float frac = ((float)j + 0.5f) * 0.0078125f;
        const float t = tmin + (frac * span);
        const float dev = ((t - 0.5f) * L) - ttof;
        if (fabsf(dev) <= 90.0f) {
            const float px = p1x + (t * dx);
            const float py = p1y + (t * dy);
            const float pz = p1z + (t * dz);
            const int vx = vox_of(px + 200.0f);
            const int vy = vox_of(py + 200.0f);
            const int vz = vox_of(pz + 200.0f);
            const float val = image[(((vx << 7) | vy) << 7) | vz];
            const float w = 0.06649038f *
                            __expf((dev * dev) * (-5.5555556e-4f));
            acc += val * w;
        }
    }
    out[lor] = acc * ((span * L) * 0.0078125f);
}

extern "C" void kernel_launch(void* const* d_in, const int* in_sizes, int n_in,
                              void* d_out, int out_size, void* d_ws, size_t ws_size,
                              hipStream_t stream) {
    const float* image = (const float*)d_in[0];   // 128^3 fp32
    const float* lors  = (const float*)d_in[1];   // N x 7 fp32
    float* out = (float*)d_out;                   // N fp32
    const int n = in_sizes[1] / 7;

    // ws layout: counts[NBUCK] | offsets[NBUCK] | tmp[n] | perm[n] |
    //            (16B align) recS[n] | ls8[2n] | (256B align) bimg[128^3]
    char* base = (char*)d_ws;
    int* counts  = (int*)base;
    int* offsets = counts + NBUCK;
    int* tmp     = offsets + NBUCK;
    int* perm    = tmp + n;
    size_t off = (size_t)(2 * NBUCK + 2 * n) * sizeof(int);
    off = (off + 15) & ~(size_t)15;
    float4* recS = (float4*)(base + off);
    float4* ls8  = (float4*)(base + off + (size_t)n * 16);
    const size_t need = off + (size_t)n * 48;
    size_t bimg_off = (need + 255) & ~(size_t)255;
    const size_t IMG_BYTES = (size_t)128 * 128 * 128 * 4;
    const size_t need_brick = bimg_off + IMG_BYTES;
    float* bimg = (float*)(base + bimg_off);

    const bool do_sort  = (ws_size >= need);
    const bool do_brick = (ws_size >= need_brick);
    const int  nb = (n + 255) / 256;

    if (!do_sort) {
        proj_fallback<<<nb, 256, 0, stream>>>(image, lors, out, n);
        return;
    }

    hipMemsetAsync(counts, 0, NBUCK * sizeof(int), stream);
    bucketrec_kernel<<<nb, 256, 0, stream>>>(lors, counts, tmp, recS, ls8, n);
    if (do_brick) {
        // block 0: scan; blocks 1..2048: brickify (128^3 / 1024)
        scan_brick_kernel<<<1 + (128 * 128 * 128) / 1024, 1024, 0, stream>>>(
            counts, offsets, image, bimg);
    } else {
        scan_kernel<<<1, 1024, 0, stream>>>(counts, offsets);
    }
    perm_kernel<<<nb, 256, 0, stream>>>(tmp, offsets, perm, n);

    const int nthreads = n * SPL;
    const int nblocks = (nthreads + 255) / 256;
    const int nb8 = ((nblocks + 7) / 8) * 8;
    if (do_brick) {
        proj_kernel<true><<<nb8, 256, 0, stream>>>(bimg, recS, ls8, perm, out,
                                                   n, nb8 >> 3);
    } else {
        proj_kernel<false><<<nb8, 256, 0, stream>>>(image, recS, ls8, perm, out,
                                                    n, nb8 >> 3);
    }
}